// Round 1
// baseline (127.682 us; speedup 1.0000x reference)
//
#include <hip/hip_runtime.h>
#include <hip/hip_bf16.h>
#include <stdint.h>

#define M_DIM 8192
#define N_DIM 2048
#define K_DIM 2048

typedef float f32x4 __attribute__((ext_vector_type(4)));
typedef short bf16x8 __attribute__((ext_vector_type(8)));

typedef const __attribute__((address_space(1))) char* gp_t;
typedef __attribute__((address_space(3))) char* lp_t;

static __device__ __forceinline__ void gload_lds16(const void* g, void* l) {
  __builtin_amdgcn_global_load_lds((gp_t)(uintptr_t)g, (lp_t)(uint32_t)(uintptr_t)l, 16, 0, 0);
}

// round-to-nearest-even f32 -> bf16 bits (exact for -1, 0, +1)
static __device__ __forceinline__ unsigned short f2bf(float f) {
  unsigned int u = __float_as_uint(f);
  unsigned int r = (u + 0x7FFFu + ((u >> 16) & 1u)) >> 16;
  return (unsigned short)r;
}

// ---------------- scale = mean(|W|), deterministic 2-stage reduction ----------------
__global__ void absum_partials(const float* __restrict__ w, float* __restrict__ partials) {
  int tid = blockIdx.x * 256 + threadIdx.x;       // 262144 threads
  const float4* w4 = (const float4*)w;            // 1048576 float4
  float s = 0.f;
#pragma unroll
  for (int i = 0; i < 4; ++i) {
    float4 v = w4[tid + i * 262144];
    s += fabsf(v.x) + fabsf(v.y) + fabsf(v.z) + fabsf(v.w);
  }
#pragma unroll
  for (int off = 32; off > 0; off >>= 1) s += __shfl_down(s, off, 64);
  __shared__ float ls[4];
  if ((threadIdx.x & 63) == 0) ls[threadIdx.x >> 6] = s;
  __syncthreads();
  if (threadIdx.x == 0) partials[blockIdx.x] = (ls[0] + ls[1]) + (ls[2] + ls[3]);
}

__global__ void finalize_scale(const float* __restrict__ partials, float* __restrict__ scale_out) {
  float s = 0.f;
#pragma unroll
  for (int i = 0; i < 4; ++i) s += partials[threadIdx.x + i * 256];
#pragma unroll
  for (int off = 32; off > 0; off >>= 1) s += __shfl_down(s, off, 64);
  __shared__ float ls[4];
  if ((threadIdx.x & 63) == 0) ls[threadIdx.x >> 6] = s;
  __syncthreads();
  if (threadIdx.x == 0)
    scale_out[0] = ((ls[0] + ls[1]) + (ls[2] + ls[3])) * (1.0f / 4194304.0f);  // mean(|W|)
}

// ---------------- W -> ternary bf16 {-1,0,1} ----------------
__global__ void quant_w(const float* __restrict__ w, const float* __restrict__ scale_p,
                        unsigned short* __restrict__ wt) {
  const float inv = 1.0f / (scale_p[0] + 1e-10f);
  int tid = blockIdx.x * 256 + threadIdx.x;       // 1048576 threads, 1 float4 each
  float4 v = ((const float4*)w)[tid];
  ushort4 o;
  float t;
  t = fminf(1.f, fmaxf(-1.f, rintf(v.x * inv))); o.x = f2bf(t);
  t = fminf(1.f, fmaxf(-1.f, rintf(v.y * inv))); o.y = f2bf(t);
  t = fminf(1.f, fmaxf(-1.f, rintf(v.z * inv))); o.z = f2bf(t);
  t = fminf(1.f, fmaxf(-1.f, rintf(v.w * inv))); o.w = f2bf(t);
  ((ushort4*)wt)[tid] = o;
}

// ---------------- x -> bf16 ----------------
__global__ void cvt_x(const float* __restrict__ x, unsigned short* __restrict__ xb) {
  int tid = blockIdx.x * 256 + threadIdx.x;       // 4194304 threads, 1 float4 each
  float4 v = ((const float4*)x)[tid];
  ushort4 o;
  o.x = f2bf(v.x); o.y = f2bf(v.y); o.z = f2bf(v.z); o.w = f2bf(v.w);
  ((ushort4*)xb)[tid] = o;
}

// ---------------- GEMM: out[M][N] = (A[M][K] @ Wt[N][K]^T) * scale + bias ----------------
// m97 structure: 128x128 tile, BK=32, 4 waves (2x2), 16x16x32 bf16 MFMA,
// global_load_lds width=16, linear LDS, 2 barriers per K-step.
__global__ void __launch_bounds__(256) gemm_bt(const unsigned short* __restrict__ A,
                                               const unsigned short* __restrict__ Bt,
                                               const float* __restrict__ bias,
                                               const float* __restrict__ scale_p,
                                               float* __restrict__ out) {
  __shared__ __align__(16) unsigned short As[128 * 32];  // 8 KB
  __shared__ __align__(16) unsigned short Bs[128 * 32];  // 8 KB
  const int tid = threadIdx.x;
  const int bm = blockIdx.x >> 4;   // 64 M-tiles
  const int bn = blockIdx.x & 15;   // 16 N-tiles
  const int m0 = bm << 7, n0 = bn << 7;
  const int lane = tid & 63, wid = tid >> 6;
  const int wr = wid >> 1, wc = wid & 1;          // 2x2 wave grid; each wave owns 64x64
  const int l15 = lane & 15, lhi = lane >> 4;

  // staging map: byte t*16 of tile -> row t/4, k-col (t%4)*8 (linear [row][BK] layout)
  const int srow = tid >> 2;
  const int scol = (tid & 3) << 3;
  const unsigned short* Ab = A + (size_t)(m0 + srow) * K_DIM + scol;
  const unsigned short* Bb = Bt + (size_t)(n0 + srow) * K_DIM + scol;
  char* AsB = (char*)As;
  char* BsB = (char*)Bs;
  char* Ad = AsB + tid * 16;   // lane0 of each wave holds the wave-uniform base
  char* Bd = BsB + tid * 16;

  // fragment read base: row = w*64 + frag*16 + (lane&15), byte = row*64 + (lane>>4)*16
  const char* Afr = AsB + (wr * 64 + l15) * 64 + lhi * 16;
  const char* Bfr = BsB + (wc * 64 + l15) * 64 + lhi * 16;

  f32x4 acc[4][4];
#pragma unroll
  for (int m = 0; m < 4; ++m)
#pragma unroll
    for (int n = 0; n < 4; ++n) {
      f32x4 z = {0.f, 0.f, 0.f, 0.f};
      acc[m][n] = z;
    }

  for (int kt = 0; kt < K_DIM; kt += 32) {
    gload_lds16(Ab + kt, Ad);                     // rows 0..63
    gload_lds16(Ab + 64 * K_DIM + kt, Ad + 4096); // rows 64..127
    gload_lds16(Bb + kt, Bd);
    gload_lds16(Bb + 64 * K_DIM + kt, Bd + 4096);
    __syncthreads();

    bf16x8 af[4], bfr[4];
#pragma unroll
    for (int m = 0; m < 4; ++m) af[m] = *(const bf16x8*)(Afr + m * 1024);
#pragma unroll
    for (int n = 0; n < 4; ++n) bfr[n] = *(const bf16x8*)(Bfr + n * 1024);
#pragma unroll
    for (int m = 0; m < 4; ++m)
#pragma unroll
      for (int n = 0; n < 4; ++n)
        acc[m][n] = __builtin_amdgcn_mfma_f32_16x16x32_bf16(af[m], bfr[n], acc[m][n], 0, 0, 0);
    __syncthreads();
  }

  // epilogue: C/D map col=lane&15, row=(lane>>4)*4+j  [verified m89/m91]
  const float scale = scale_p[0];
#pragma unroll
  for (int n = 0; n < 4; ++n) {
    const int col = n0 + wc * 64 + n * 16 + l15;
    const float bv = bias[col];
#pragma unroll
    for (int m = 0; m < 4; ++m) {
      const int r0 = m0 + wr * 64 + m * 16 + lhi * 4;
      float* op = out + (size_t)r0 * N_DIM + col;
#pragma unroll
      for (int j = 0; j < 4; ++j) op[(size_t)j * N_DIM] = acc[m][n][j] * scale + bv;
    }
  }
}

extern "C" void kernel_launch(void* const* d_in, const int* in_sizes, int n_in,
                              void* d_out, int out_size, void* d_ws, size_t ws_size,
                              hipStream_t stream) {
  (void)in_sizes; (void)n_in; (void)out_size; (void)ws_size;
  const float* x    = (const float*)d_in[0];   // [4][2048][2048] f32
  const float* w    = (const float*)d_in[1];   // [2048][2048] f32
  const float* bias = (const float*)d_in[2];   // [2048] f32
  float* out = (float*)d_out;                  // [4][2048][2048] f32

  // workspace layout
  float* partials = (float*)d_ws;                                        // 1024 f32
  float* scale_slot = partials + 1024;                                   // 1 f32
  unsigned short* wt = (unsigned short*)((char*)d_ws + 8192);            // 8 MB bf16 W_t
  unsigned short* xb = (unsigned short*)((char*)d_ws + 8192 + (size_t)N_DIM * K_DIM * 2);  // 32 MB bf16 x

  absum_partials<<<1024, 256, 0, stream>>>(w, partials);
  finalize_scale<<<1, 256, 0, stream>>>(partials, scale_slot);
  quant_w<<<4096, 256, 0, stream>>>(w, scale_slot, wt);
  cvt_x<<<16384, 256, 0, stream>>>(x, xb);
  gemm_bt<<<1024, 256, 0, stream>>>(xb, wt, bias, scale_slot, out);
}

// Round 2
// 100.362 us; speedup vs baseline: 1.2722x; 1.2722x over previous
//
#include <hip/hip_runtime.h>
#include <hip/hip_bf16.h>
#include <stdint.h>

#define M_DIM 8192
#define N_DIM 2048
#define K_DIM 2048
#define NT    (K_DIM / 64)   // 32 K-tiles of BK=64

typedef float f32x4 __attribute__((ext_vector_type(4)));
typedef short bf16x8 __attribute__((ext_vector_type(8)));

typedef const __attribute__((address_space(1))) char* gp_t;
typedef __attribute__((address_space(3))) char* lp_t;

static __device__ __forceinline__ void gload_lds16(const void* g, void* l) {
  __builtin_amdgcn_global_load_lds((gp_t)(uintptr_t)g, (lp_t)(uint32_t)(uintptr_t)l, 16, 0, 0);
}

// round-to-nearest-even f32 -> bf16 bits (exact for -1, 0, +1)
static __device__ __forceinline__ unsigned short f2bf(float f) {
  unsigned int u = __float_as_uint(f);
  unsigned int r = (u + 0x7FFFu + ((u >> 16) & 1u)) >> 16;
  return (unsigned short)r;
}

// ---------------- scale = mean(|W|), deterministic 2-stage reduction ----------------
__global__ void absum_partials(const float* __restrict__ w, float* __restrict__ partials) {
  int tid = blockIdx.x * 256 + threadIdx.x;
  const float4* w4 = (const float4*)w;
  float s = 0.f;
#pragma unroll
  for (int i = 0; i < 4; ++i) {
    float4 v = w4[tid + i * 262144];
    s += fabsf(v.x) + fabsf(v.y) + fabsf(v.z) + fabsf(v.w);
  }
#pragma unroll
  for (int off = 32; off > 0; off >>= 1) s += __shfl_down(s, off, 64);
  __shared__ float ls[4];
  if ((threadIdx.x & 63) == 0) ls[threadIdx.x >> 6] = s;
  __syncthreads();
  if (threadIdx.x == 0) partials[blockIdx.x] = (ls[0] + ls[1]) + (ls[2] + ls[3]);
}

__global__ void finalize_scale(const float* __restrict__ partials, float* __restrict__ scale_out) {
  float s = 0.f;
#pragma unroll
  for (int i = 0; i < 4; ++i) s += partials[threadIdx.x + i * 256];
#pragma unroll
  for (int off = 32; off > 0; off >>= 1) s += __shfl_down(s, off, 64);
  __shared__ float ls[4];
  if ((threadIdx.x & 63) == 0) ls[threadIdx.x >> 6] = s;
  __syncthreads();
  if (threadIdx.x == 0)
    scale_out[0] = ((ls[0] + ls[1]) + (ls[2] + ls[3])) * (1.0f / 4194304.0f);
}

// ---------------- W -> ternary bf16 {-1,0,1} ----------------
__global__ void quant_w(const float* __restrict__ w, const float* __restrict__ scale_p,
                        unsigned short* __restrict__ wt) {
  const float inv = 1.0f / (scale_p[0] + 1e-10f);
  int tid = blockIdx.x * 256 + threadIdx.x;
  float4 v = ((const float4*)w)[tid];
  ushort4 o;
  float t;
  t = fminf(1.f, fmaxf(-1.f, rintf(v.x * inv))); o.x = f2bf(t);
  t = fminf(1.f, fmaxf(-1.f, rintf(v.y * inv))); o.y = f2bf(t);
  t = fminf(1.f, fmaxf(-1.f, rintf(v.z * inv))); o.z = f2bf(t);
  t = fminf(1.f, fmaxf(-1.f, rintf(v.w * inv))); o.w = f2bf(t);
  ((ushort4*)wt)[tid] = o;
}

// ---------------- x -> bf16 ----------------
__global__ void cvt_x(const float* __restrict__ x, unsigned short* __restrict__ xb) {
  int tid = blockIdx.x * 256 + threadIdx.x;
  float4 v = ((const float4*)x)[tid];
  ushort4 o;
  o.x = f2bf(v.x); o.y = f2bf(v.y); o.z = f2bf(v.z); o.w = f2bf(v.w);
  ((ushort4*)xb)[tid] = o;
}

// ---------------- 256x256 8-phase GEMM: out = (A @ Bt^T)*scale + bias ----------------
// BM=BN=256, BK=64, 8 waves (2Mx4N), 512 thr, LDS 128KB dbuf, st_16x32 swizzle,
// counted vmcnt(4) once per K-tile, setprio around MFMA, XCD-aware block swizzle.

#define VMCNT(n) asm volatile("s_waitcnt vmcnt(" #n ")" ::: "memory")
#define FENCE    asm volatile("" ::: "memory")
#define BARRIER  do { FENCE; __builtin_amdgcn_s_barrier(); FENCE; } while (0)

#define READ_A(mh)                                                                          \
  do {                                                                                      \
    _Pragma("unroll") for (int i = 0; i < 4; ++i) {                                         \
      a_r[i][0] = *(const bf16x8*)(curA + (wr * 128 + (mh) * 64 + i * 16) * 128 + rd_off);  \
      a_r[i][1] = *(const bf16x8*)(curA + (wr * 128 + (mh) * 64 + i * 16) * 128 + 64 + rd_off); \
    }                                                                                       \
  } while (0)

#define READ_B(nh, br)                                                                      \
  do {                                                                                      \
    _Pragma("unroll") for (int j = 0; j < 2; ++j) {                                         \
      br[j][0] = *(const bf16x8*)(curB + (wc * 64 + (nh) * 32 + j * 16) * 128 + rd_off);    \
      br[j][1] = *(const bf16x8*)(curB + (wc * 64 + (nh) * 32 + j * 16) * 128 + 64 + rd_off); \
    }                                                                                       \
  } while (0)

#define MFMA_PH(mh, nh, br)                                                                 \
  do {                                                                                      \
    __builtin_amdgcn_s_setprio(1);                                                          \
    _Pragma("unroll") for (int i = 0; i < 4; ++i)                                           \
      _Pragma("unroll") for (int j = 0; j < 2; ++j)                                         \
        acc[(mh) * 4 + i][(nh) * 2 + j] = __builtin_amdgcn_mfma_f32_16x16x32_bf16(          \
            a_r[i][0], br[j][0], acc[(mh) * 4 + i][(nh) * 2 + j], 0, 0, 0);                 \
    _Pragma("unroll") for (int i = 0; i < 4; ++i)                                           \
      _Pragma("unroll") for (int j = 0; j < 2; ++j)                                         \
        acc[(mh) * 4 + i][(nh) * 2 + j] = __builtin_amdgcn_mfma_f32_16x16x32_bf16(          \
            a_r[i][1], br[j][1], acc[(mh) * 4 + i][(nh) * 2 + j], 0, 0, 0);                 \
    __builtin_amdgcn_s_setprio(0);                                                          \
  } while (0)

// stage half-tiles: r in 0..3 covers rows (tid>>3)+r*64; inverse-swizzled global source
#define SA(bufsel, r) gload_lds16(Ag + offA[r] + ktA, ldsb + (bufsel) * 65536 + tid * 16 + (r) * 8192)
#define SB(bufsel, r) gload_lds16(Bg + offB[r] + ktB, ldsb + (bufsel) * 65536 + 32768 + tid * 16 + (r) * 8192)

__global__ void __launch_bounds__(512, 2)
gemm_bt(const unsigned short* __restrict__ A, const unsigned short* __restrict__ Bt,
        const float* __restrict__ bias, const float* __restrict__ scale_p,
        float* __restrict__ out) {
  __shared__ __align__(16) char lds_raw[131072];
  char* ldsb = (char*)lds_raw;

  const int tid = threadIdx.x;                 // 0..511
  const int lane = tid & 63;
  const int wid = tid >> 6;                    // 0..7
  const int wr = wid >> 2;                     // 0..1
  const int wc = wid & 3;                      // 0..3
  const int l15 = lane & 15, lhi = lane >> 4;
  // st_16x32 read offset: byte ^= ((byte>>9)&1)<<5  (bit9 = row bit2 = l15 bit2)
  const int rd_off = l15 * 128 + ((lhi * 16) ^ (((l15 >> 2) & 1) << 5));

  // XCD-aware swizzle: 256 blocks, 8 XCDs x 32-chunk; bm-major inside chunk
  const int bid = blockIdx.x;
  const int swz = (bid & 7) * 32 + (bid >> 3);
  const int bm = swz >> 3;                     // 0..31
  const int bn = swz & 7;                      // 0..7
  const int m0 = bm << 8, n0 = bn << 8;

  // staging map: thread stages bytes tid*16 + r*8192 of each 32KB tile (linear dest),
  // reading global at the swizzled column so swizzled ds_reads see linear data.
  const int srow = tid >> 3;                                       // 0..63
  const int scol = ((tid & 7) << 4) ^ (((tid >> 5) & 1) << 5);     // inverse swizzle
  const char* Ag = (const char*)A;
  const char* Bg = (const char*)Bt;
  uint32_t offA[4], offB[4];
#pragma unroll
  for (int r = 0; r < 4; ++r) {
    offA[r] = (uint32_t)(m0 + srow + r * 64) * (K_DIM * 2) + scol;
    offB[r] = (uint32_t)(n0 + srow + r * 64) * (K_DIM * 2) + scol;
  }
  uint32_t ktA = 0, ktB = 0;   // byte offset along K of next tile to stage (BK*2 = 128)

  f32x4 acc[8][4];
#pragma unroll
  for (int m = 0; m < 8; ++m)
#pragma unroll
    for (int n = 0; n < 4; ++n) {
      f32x4 z = {0.f, 0.f, 0.f, 0.f};
      acc[m][n] = z;
    }

  // ---- prologue: stage T0 (A+B -> buf0), T1.B -> buf1; drain T0, keep T1.B in flight
  SA(0, 0); SA(0, 1); SA(0, 2); SA(0, 3);
  SB(0, 0); SB(0, 1); SB(0, 2); SB(0, 3);
  ktB = 128;
  SB(1, 0); SB(1, 1); SB(1, 2); SB(1, 3);
  ktA = 128; ktB = 256;
  VMCNT(4);
  BARRIER;

  bf16x8 a_r[4][2], b0[2][2], b1[2][2];

  for (int t = 0; t < NT; ++t) {
    const int cb = t & 1;
    const char* curA = ldsb + cb * 65536;
    const char* curB = curA + 32768;

    // Q1: read A[mh0], B[nh0]; stage T(t+1).Ah0 -> buf[cb^1] (A freed after Q3(t-1))
    READ_A(0);
    READ_B(0, b0);
    if (t < NT - 1) { SA(cb ^ 1, 0); SA(cb ^ 1, 1); }
    BARRIER;
    MFMA_PH(0, 0, b0);
    BARRIER;

    // Q2: read B[nh1]; stage T(t+1).Ah1
    READ_B(1, b1);
    if (t < NT - 1) { SA(cb ^ 1, 2); SA(cb ^ 1, 3); ktA += 128; }
    BARRIER;
    MFMA_PH(0, 1, b1);
    BARRIER;

    // Q3: read A[mh1]; stage T(t+2).Bh0 -> buf[cb] (B freed after Q2(t))
    READ_A(1);
    if (t < NT - 2) { SB(cb, 0); SB(cb, 1); }
    BARRIER;
    MFMA_PH(1, 0, b0);
    BARRIER;

    // Q4: stage T(t+2).Bh1; counted drain: T(t+1) complete, T(t+2).B stays in flight
    if (t < NT - 2) {
      SB(cb, 2); SB(cb, 3); ktB += 128;
      VMCNT(4);
    } else {
      VMCNT(0);
    }
    BARRIER;
    MFMA_PH(1, 1, b1);
    BARRIER;
  }

  // ---- epilogue: C/D map col=lane&15, row=(lane>>4)*4+j ; fuse *scale + bias
  const float scale = scale_p[0];
#pragma unroll
  for (int n = 0; n < 4; ++n) {
    const int col = n0 + wc * 64 + n * 16 + l15;
    const float bv = bias[col];
#pragma unroll
    for (int m = 0; m < 8; ++m) {
      const int r0 = m0 + wr * 128 + m * 16 + lhi * 4;
      float* op = out + (size_t)r0 * N_DIM + col;
#pragma unroll
      for (int j = 0; j < 4; ++j) op[(size_t)j * N_DIM] = acc[m][n][j] * scale + bv;
    }
  }
}

extern "C" void kernel_launch(void* const* d_in, const int* in_sizes, int n_in,
                              void* d_out, int out_size, void* d_ws, size_t ws_size,
                              hipStream_t stream) {
  (void)in_sizes; (void)n_in; (void)out_size; (void)ws_size;
  const float* x    = (const float*)d_in[0];   // [4][2048][2048] f32
  const float* w    = (const float*)d_in[1];   // [2048][2048] f32
  const float* bias = (const float*)d_in[2];   // [2048] f32
  float* out = (float*)d_out;                  // [4][2048][2048] f32

  float* partials = (float*)d_ws;
  float* scale_slot = partials + 1024;
  unsigned short* wt = (unsigned short*)((char*)d_ws + 8192);
  unsigned short* xb = (unsigned short*)((char*)d_ws + 8192 + (size_t)N_DIM * K_DIM * 2);

  absum_partials<<<1024, 256, 0, stream>>>(w, partials);
  finalize_scale<<<1, 256, 0, stream>>>(partials, scale_slot);
  quant_w<<<4096, 256, 0, stream>>>(w, scale_slot, wt);
  cvt_x<<<16384, 256, 0, stream>>>(x, xb);
  gemm_bt<<<256, 512, 0, stream>>>(xb, wt, bias, scale_slot, out);
}

// Round 3
// 87.024 us; speedup vs baseline: 1.4672x; 1.1533x over previous
//
#include <hip/hip_runtime.h>
#include <hip/hip_bf16.h>
#include <stdint.h>

#define M_DIM 8192
#define N_DIM 2048
#define K_DIM 2048
#define NT    (K_DIM / 64)   // 32 K-tiles of BK=64

typedef float f32x4 __attribute__((ext_vector_type(4)));
typedef short bf16x8 __attribute__((ext_vector_type(8)));

typedef const __attribute__((address_space(1))) char* gp_t;
typedef __attribute__((address_space(3))) char* lp_t;

static __device__ __forceinline__ void gload_lds16(const void* g, void* l) {
  __builtin_amdgcn_global_load_lds((gp_t)(uintptr_t)g, (lp_t)(uint32_t)(uintptr_t)l, 16, 0, 0);
}

// round-to-nearest-even f32 -> bf16 bits (exact for -1, 0, +1)
static __device__ __forceinline__ unsigned short f2bf(float f) {
  unsigned int u = __float_as_uint(f);
  unsigned int r = (u + 0x7FFFu + ((u >> 16) & 1u)) >> 16;
  return (unsigned short)r;
}

// ---------------- fused: x -> bf16 (blocks 0..16383) + |W| partials (blocks 16384..17407) ----
__global__ void cvt_x_absum(const float* __restrict__ x, unsigned short* __restrict__ xb,
                            const float* __restrict__ w, float* __restrict__ partials) {
  const int b = blockIdx.x;
  if (b < 16384) {
    int tid = b * 256 + threadIdx.x;
    float4 v = ((const float4*)x)[tid];
    ushort4 o;
    o.x = f2bf(v.x); o.y = f2bf(v.y); o.z = f2bf(v.z); o.w = f2bf(v.w);
    ((ushort4*)xb)[tid] = o;
  } else {
    int tid = (b - 16384) * 256 + threadIdx.x;
    const float4* w4 = (const float4*)w;
    float s = 0.f;
#pragma unroll
    for (int i = 0; i < 4; ++i) {
      float4 v = w4[tid + i * 262144];
      s += fabsf(v.x) + fabsf(v.y) + fabsf(v.z) + fabsf(v.w);
    }
#pragma unroll
    for (int off = 32; off > 0; off >>= 1) s += __shfl_down(s, off, 64);
    __shared__ float ls[4];
    if ((threadIdx.x & 63) == 0) ls[threadIdx.x >> 6] = s;
    __syncthreads();
    if (threadIdx.x == 0) partials[b - 16384] = (ls[0] + ls[1]) + (ls[2] + ls[3]);
  }
}

// ---------------- W -> ternary bf16 {-1,0,1}; each block self-reduces scale ----------------
__global__ void quant_w(const float* __restrict__ w, const float* __restrict__ partials,
                        unsigned short* __restrict__ wt, float* __restrict__ scale_out) {
  __shared__ float ls[4];
  float s = 0.f;
#pragma unroll
  for (int i = 0; i < 4; ++i) s += partials[threadIdx.x + i * 256];
#pragma unroll
  for (int off = 32; off > 0; off >>= 1) s += __shfl_down(s, off, 64);
  if ((threadIdx.x & 63) == 0) ls[threadIdx.x >> 6] = s;
  __syncthreads();
  const float scale = ((ls[0] + ls[1]) + (ls[2] + ls[3])) * (1.0f / 4194304.0f);
  if (blockIdx.x == 0 && threadIdx.x == 0) scale_out[0] = scale;

  const float inv = 1.0f / (scale + 1e-10f);
  int tid = blockIdx.x * 256 + threadIdx.x;
  float4 v = ((const float4*)w)[tid];
  ushort4 o;
  float t;
  t = fminf(1.f, fmaxf(-1.f, rintf(v.x * inv))); o.x = f2bf(t);
  t = fminf(1.f, fmaxf(-1.f, rintf(v.y * inv))); o.y = f2bf(t);
  t = fminf(1.f, fmaxf(-1.f, rintf(v.z * inv))); o.z = f2bf(t);
  t = fminf(1.f, fmaxf(-1.f, rintf(v.w * inv))); o.w = f2bf(t);
  ((ushort4*)wt)[tid] = o;
}

// ---------------- 256x256 8-phase GEMM: out = (A @ Bt^T)*scale + bias ----------------
// BM=BN=256, BK=64, 8 waves (2Mx4N), 512 thr, LDS 128KB dbuf,
// FULL 3-bit XOR swizzle: byte ^= (row&7)<<4  (G4: 128B rows, b128 reads -> 2-way = free),
// counted vmcnt(4) once per K-tile, setprio around MFMA, XCD-aware block swizzle.

#define VMCNT(n) asm volatile("s_waitcnt vmcnt(" #n ")" ::: "memory")
#define FENCE    asm volatile("" ::: "memory")
#define BARRIER  do { FENCE; __builtin_amdgcn_s_barrier(); FENCE; } while (0)

#define READ_A(mh)                                                                              \
  do {                                                                                          \
    _Pragma("unroll") for (int i = 0; i < 4; ++i) {                                             \
      a_r[i][0] = *(const bf16x8*)(curA + (wr * 128 + (mh) * 64 + i * 16) * 128 + rd0);         \
      a_r[i][1] = *(const bf16x8*)(curA + (wr * 128 + (mh) * 64 + i * 16) * 128 + rd1);         \
    }                                                                                           \
  } while (0)

#define READ_B(nh, br)                                                                          \
  do {                                                                                          \
    _Pragma("unroll") for (int j = 0; j < 2; ++j) {                                             \
      br[j][0] = *(const bf16x8*)(curB + (wc * 64 + (nh) * 32 + j * 16) * 128 + rd0);           \
      br[j][1] = *(const bf16x8*)(curB + (wc * 64 + (nh) * 32 + j * 16) * 128 + rd1);           \
    }                                                                                           \
  } while (0)

#define MFMA_PH(mh, nh, br)                                                                     \
  do {                                                                                          \
    __builtin_amdgcn_s_setprio(1);                                                              \
    _Pragma("unroll") for (int i = 0; i < 4; ++i)                                               \
      _Pragma("unroll") for (int j = 0; j < 2; ++j)                                             \
        acc[(mh) * 4 + i][(nh) * 2 + j] = __builtin_amdgcn_mfma_f32_16x16x32_bf16(              \
            a_r[i][0], br[j][0], acc[(mh) * 4 + i][(nh) * 2 + j], 0, 0, 0);                     \
    _Pragma("unroll") for (int i = 0; i < 4; ++i)                                               \
      _Pragma("unroll") for (int j = 0; j < 2; ++j)                                             \
        acc[(mh) * 4 + i][(nh) * 2 + j] = __builtin_amdgcn_mfma_f32_16x16x32_bf16(              \
            a_r[i][1], br[j][1], acc[(mh) * 4 + i][(nh) * 2 + j], 0, 0, 0);                     \
    __builtin_amdgcn_s_setprio(0);                                                              \
  } while (0)

// stage half-tiles: linear LDS dest (gload_lds requirement), inverse-swizzled global source
#define SA(bufsel, r) gload_lds16(Ag + offA[r] + ktA, ldsb + (bufsel) * 65536 + tid * 16 + (r) * 8192)
#define SB(bufsel, r) gload_lds16(Bg + offB[r] + ktB, ldsb + (bufsel) * 65536 + 32768 + tid * 16 + (r) * 8192)

__global__ void __launch_bounds__(512, 2)
gemm_bt(const unsigned short* __restrict__ A, const unsigned short* __restrict__ Bt,
        const float* __restrict__ bias, const float* __restrict__ scale_p,
        float* __restrict__ out) {
  __shared__ __align__(16) char lds_raw[131072];
  char* ldsb = (char*)lds_raw;

  const int tid = threadIdx.x;                 // 0..511
  const int lane = tid & 63;
  const int wid = tid >> 6;                    // 0..7
  const int wr = wid >> 2;                     // 0..1
  const int wc = wid & 3;                      // 0..3
  const int l15 = lane & 15, lhi = lane >> 4;

  // 3-bit read swizzle: byte ^= (row&7)<<4 ; row&7 == l15&7 (row offsets are x16)
  const int swzl = (l15 & 7) << 4;
  const int rd0 = l15 * 128 + ((lhi * 16) ^ swzl);          // k-half 0
  const int rd1 = l15 * 128 + (((lhi * 16) ^ 64) ^ swzl);   // k-half 1 (XOR, not +64!)

  // XCD-aware swizzle: 256 blocks, 8 XCDs x 32-chunk; bm-major inside chunk
  const int bid = blockIdx.x;
  const int swz = (bid & 7) * 32 + (bid >> 3);
  const int bm = swz >> 3;                     // 0..31
  const int bn = swz & 7;                      // 0..7
  const int m0 = bm << 8, n0 = bn << 8;

  // staging: thread stages LDS row srow+r*64, colbyte (tid&7)*16 (linear dest);
  // global source column inverse-swizzled so swizzled ds_reads see linear data.
  const int srow = tid >> 3;                                          // 0..63
  const int scol = (((tid & 7) ^ ((tid >> 3) & 7)) << 4);             // cb ^ (row&7)<<4
  const char* Ag = (const char*)A;
  const char* Bg = (const char*)Bt;
  uint32_t offA[4], offB[4];
#pragma unroll
  for (int r = 0; r < 4; ++r) {
    offA[r] = (uint32_t)(m0 + srow + r * 64) * (K_DIM * 2) + scol;
    offB[r] = (uint32_t)(n0 + srow + r * 64) * (K_DIM * 2) + scol;
  }
  uint32_t ktA = 0, ktB = 0;   // byte offset along K of next tile to stage (BK*2 = 128)

  f32x4 acc[8][4];
#pragma unroll
  for (int m = 0; m < 8; ++m)
#pragma unroll
    for (int n = 0; n < 4; ++n) {
      f32x4 z = {0.f, 0.f, 0.f, 0.f};
      acc[m][n] = z;
    }

  // ---- prologue: stage T0 (A+B -> buf0), T1.B -> buf1; drain T0, keep T1.B in flight
  SA(0, 0); SA(0, 1); SA(0, 2); SA(0, 3);
  SB(0, 0); SB(0, 1); SB(0, 2); SB(0, 3);
  ktB = 128;
  SB(1, 0); SB(1, 1); SB(1, 2); SB(1, 3);
  ktA = 128; ktB = 256;
  VMCNT(4);
  BARRIER;

  bf16x8 a_r[4][2], b0[2][2], b1[2][2];

  for (int t = 0; t < NT; ++t) {
    const int cb = t & 1;
    const char* curA = ldsb + cb * 65536;
    const char* curB = curA + 32768;

    // Q1: read A[mh0], B[nh0]; stage T(t+1).Ah0 -> buf[cb^1]
    READ_A(0);
    READ_B(0, b0);
    if (t < NT - 1) { SA(cb ^ 1, 0); SA(cb ^ 1, 1); }
    BARRIER;
    MFMA_PH(0, 0, b0);
    BARRIER;

    // Q2: read B[nh1]; stage T(t+1).Ah1
    READ_B(1, b1);
    if (t < NT - 1) { SA(cb ^ 1, 2); SA(cb ^ 1, 3); ktA += 128; }
    BARRIER;
    MFMA_PH(0, 1, b1);
    BARRIER;

    // Q3: read A[mh1]; stage T(t+2).Bh0 -> buf[cb]
    READ_A(1);
    if (t < NT - 2) { SB(cb, 0); SB(cb, 1); }
    BARRIER;
    MFMA_PH(1, 0, b0);
    BARRIER;

    // Q4: stage T(t+2).Bh1; counted drain: T(t+1) complete, T(t+2).B stays in flight
    if (t < NT - 2) {
      SB(cb, 2); SB(cb, 3); ktB += 128;
      VMCNT(4);
    } else {
      VMCNT(0);
    }
    BARRIER;
    MFMA_PH(1, 1, b1);
    BARRIER;
  }

  // ---- epilogue: C/D map col=lane&15, row=(lane>>4)*4+j ; fuse *scale + bias
  const float scale = scale_p[0];
#pragma unroll
  for (int n = 0; n < 4; ++n) {
    const int col = n0 + wc * 64 + n * 16 + l15;
    const float bv = bias[col];
#pragma unroll
    for (int m = 0; m < 8; ++m) {
      const int r0 = m0 + wr * 128 + m * 16 + lhi * 4;
      float* op = out + (size_t)r0 * N_DIM + col;
#pragma unroll
      for (int j = 0; j < 4; ++j) op[(size_t)j * N_DIM] = acc[m][n][j] * scale + bv;
    }
  }
}

extern "C" void kernel_launch(void* const* d_in, const int* in_sizes, int n_in,
                              void* d_out, int out_size, void* d_ws, size_t ws_size,
                              hipStream_t stream) {
  (void)in_sizes; (void)n_in; (void)out_size; (void)ws_size;
  const float* x    = (const float*)d_in[0];   // [4][2048][2048] f32
  const float* w    = (const float*)d_in[1];   // [2048][2048] f32
  const float* bias = (const float*)d_in[2];   // [2048] f32
  float* out = (float*)d_out;                  // [4][2048][2048] f32

  float* partials = (float*)d_ws;                              // 1024 f32
  float* scale_slot = partials + 1024;                         // 1 f32
  unsigned short* wt = (unsigned short*)((char*)d_ws + 8192);  // 8 MB bf16 W_t
  unsigned short* xb = (unsigned short*)((char*)d_ws + 8192 + (size_t)N_DIM * K_DIM * 2);  // 32 MB

  cvt_x_absum<<<17408, 256, 0, stream>>>(x, xb, w, partials);
  quant_w<<<4096, 256, 0, stream>>>(w, partials, wt, scale_slot);
  gemm_bt<<<256, 512, 0, stream>>>(xb, wt, bias, scale_slot, out);
}

// Round 4
// 83.921 us; speedup vs baseline: 1.5214x; 1.0370x over previous
//
#include <hip/hip_runtime.h>
#include <hip/hip_bf16.h>
#include <stdint.h>

#define M_DIM 8192
#define N_DIM 2048
#define K_DIM 2048
#define NT    (K_DIM / 64)   // 32 K-tiles of BK=64

typedef float f32x4 __attribute__((ext_vector_type(4)));
typedef short bf16x8 __attribute__((ext_vector_type(8)));

typedef const __attribute__((address_space(1))) char* gp_t;
typedef __attribute__((address_space(3))) char* lp_t;

static __device__ __forceinline__ void gload_lds16(const void* g, void* l) {
  __builtin_amdgcn_global_load_lds((gp_t)(uintptr_t)g, (lp_t)(uint32_t)(uintptr_t)l, 16, 0, 0);
}

// round-to-nearest-even f32 -> bf16 bits (exact for -1, 0, +1)
static __device__ __forceinline__ unsigned short f2bf(float f) {
  unsigned int u = __float_as_uint(f);
  unsigned int r = (u + 0x7FFFu + ((u >> 16) & 1u)) >> 16;
  return (unsigned short)r;
}

// ---------------- fused: x -> bf16 (blocks 0..16383) + |W| partials (blocks 16384..17407) ----
__global__ void cvt_x_absum(const float* __restrict__ x, unsigned short* __restrict__ xb,
                            const float* __restrict__ w, float* __restrict__ partials) {
  const int b = blockIdx.x;
  if (b < 16384) {
    int tid = b * 256 + threadIdx.x;
    float4 v = ((const float4*)x)[tid];
    ushort4 o;
    o.x = f2bf(v.x); o.y = f2bf(v.y); o.z = f2bf(v.z); o.w = f2bf(v.w);
    ((ushort4*)xb)[tid] = o;
  } else {
    int tid = (b - 16384) * 256 + threadIdx.x;
    const float4* w4 = (const float4*)w;
    float s = 0.f;
#pragma unroll
    for (int i = 0; i < 4; ++i) {
      float4 v = w4[tid + i * 262144];
      s += fabsf(v.x) + fabsf(v.y) + fabsf(v.z) + fabsf(v.w);
    }
#pragma unroll
    for (int off = 32; off > 0; off >>= 1) s += __shfl_down(s, off, 64);
    __shared__ float ls[4];
    if ((threadIdx.x & 63) == 0) ls[threadIdx.x >> 6] = s;
    __syncthreads();
    if (threadIdx.x == 0) partials[b - 16384] = (ls[0] + ls[1]) + (ls[2] + ls[3]);
  }
}

// ---------------- W -> ternary bf16 {-1,0,1}; each block self-reduces scale ----------------
__global__ void quant_w(const float* __restrict__ w, const float* __restrict__ partials,
                        unsigned short* __restrict__ wt, float* __restrict__ scale_out) {
  __shared__ float ls[4];
  float s = 0.f;
#pragma unroll
  for (int i = 0; i < 4; ++i) s += partials[threadIdx.x + i * 256];
#pragma unroll
  for (int off = 32; off > 0; off >>= 1) s += __shfl_down(s, off, 64);
  if ((threadIdx.x & 63) == 0) ls[threadIdx.x >> 6] = s;
  __syncthreads();
  const float scale = ((ls[0] + ls[1]) + (ls[2] + ls[3])) * (1.0f / 4194304.0f);
  if (blockIdx.x == 0 && threadIdx.x == 0) scale_out[0] = scale;

  const float inv = 1.0f / (scale + 1e-10f);
  int tid = blockIdx.x * 256 + threadIdx.x;
  float4 v = ((const float4*)w)[tid];
  ushort4 o;
  float t;
  t = fminf(1.f, fmaxf(-1.f, rintf(v.x * inv))); o.x = f2bf(t);
  t = fminf(1.f, fmaxf(-1.f, rintf(v.y * inv))); o.y = f2bf(t);
  t = fminf(1.f, fmaxf(-1.f, rintf(v.z * inv))); o.z = f2bf(t);
  t = fminf(1.f, fmaxf(-1.f, rintf(v.w * inv))); o.w = f2bf(t);
  ((ushort4*)wt)[tid] = o;
}

// ---------------- 256x256 GEMM, 2 barriers per K-tile: out = (A @ Bt^T)*scale + bias -------
// BM=BN=256, BK=64, 8 waves (2Mx4N), 512 thr, LDS 128KB dbuf,
// 3-bit XOR swizzle byte^=(row&7)<<4 (bank-conflict-free, verified r3: SQ_LDS_BANK_CONFLICT=0),
// counted vmcnt(4) once per K-tile; ONLY the two hazard-bearing barriers kept:
//   mid-tile (B[t] consumed before SB overwrites B-region of current buf)
//   tile-end (A[t] consumed before next tile's SA overwrites A-region; T(t+1) vmcnt-drained)

#define VMCNT(n) asm volatile("s_waitcnt vmcnt(" #n ")" ::: "memory")
#define FENCE    asm volatile("" ::: "memory")
#define BARRIER  do { FENCE; __builtin_amdgcn_s_barrier(); FENCE; } while (0)

#define READ_A(mh)                                                                              \
  do {                                                                                          \
    _Pragma("unroll") for (int i = 0; i < 4; ++i) {                                             \
      a_r[i][0] = *(const bf16x8*)(curA + (wr * 128 + (mh) * 64 + i * 16) * 128 + rd0);         \
      a_r[i][1] = *(const bf16x8*)(curA + (wr * 128 + (mh) * 64 + i * 16) * 128 + rd1);         \
    }                                                                                           \
  } while (0)

#define READ_B(nh, br)                                                                          \
  do {                                                                                          \
    _Pragma("unroll") for (int j = 0; j < 2; ++j) {                                             \
      br[j][0] = *(const bf16x8*)(curB + (wc * 64 + (nh) * 32 + j * 16) * 128 + rd0);           \
      br[j][1] = *(const bf16x8*)(curB + (wc * 64 + (nh) * 32 + j * 16) * 128 + rd1);           \
    }                                                                                           \
  } while (0)

#define MFMA_PH(mh, nh, br)                                                                     \
  do {                                                                                          \
    __builtin_amdgcn_s_setprio(1);                                                              \
    _Pragma("unroll") for (int i = 0; i < 4; ++i)                                               \
      _Pragma("unroll") for (int j = 0; j < 2; ++j)                                             \
        acc[(mh) * 4 + i][(nh) * 2 + j] = __builtin_amdgcn_mfma_f32_16x16x32_bf16(              \
            a_r[i][0], br[j][0], acc[(mh) * 4 + i][(nh) * 2 + j], 0, 0, 0);                     \
    _Pragma("unroll") for (int i = 0; i < 4; ++i)                                               \
      _Pragma("unroll") for (int j = 0; j < 2; ++j)                                             \
        acc[(mh) * 4 + i][(nh) * 2 + j] = __builtin_amdgcn_mfma_f32_16x16x32_bf16(              \
            a_r[i][1], br[j][1], acc[(mh) * 4 + i][(nh) * 2 + j], 0, 0, 0);                     \
    __builtin_amdgcn_s_setprio(0);                                                              \
  } while (0)

// stage half-tiles: linear LDS dest (gload_lds requirement), inverse-swizzled global source
#define SA(bufsel, r) gload_lds16(Ag + offA[r] + ktA, ldsb + (bufsel) * 65536 + tid * 16 + (r) * 8192)
#define SB(bufsel, r) gload_lds16(Bg + offB[r] + ktB, ldsb + (bufsel) * 65536 + 32768 + tid * 16 + (r) * 8192)

__global__ void __launch_bounds__(512, 2)
gemm_bt(const unsigned short* __restrict__ A, const unsigned short* __restrict__ Bt,
        const float* __restrict__ bias, const float* __restrict__ scale_p,
        float* __restrict__ out) {
  __shared__ __align__(16) char lds_raw[131072];
  char* ldsb = (char*)lds_raw;

  const int tid = threadIdx.x;                 // 0..511
  const int lane = tid & 63;
  const int wid = tid >> 6;                    // 0..7
  const int wr = wid >> 2;                     // 0..1
  const int wc = wid & 3;                      // 0..3
  const int l15 = lane & 15, lhi = lane >> 4;

  // 3-bit read swizzle: byte ^= (row&7)<<4 ; row&7 == l15&7 (row offsets are x16)
  const int swzl = (l15 & 7) << 4;
  const int rd0 = l15 * 128 + ((lhi * 16) ^ swzl);          // k-half 0
  const int rd1 = l15 * 128 + (((lhi * 16) ^ 64) ^ swzl);   // k-half 1 (XOR, not +64!)

  // XCD-aware swizzle: 256 blocks, 8 XCDs x 32-chunk; bm-major inside chunk
  const int bid = blockIdx.x;
  const int swz = (bid & 7) * 32 + (bid >> 3);
  const int bm = swz >> 3;                     // 0..31
  const int bn = swz & 7;                      // 0..7
  const int m0 = bm << 8, n0 = bn << 8;

  // staging: thread stages LDS row srow+r*64, colbyte (tid&7)*16 (linear dest);
  // global source column inverse-swizzled so swizzled ds_reads see linear data.
  const int srow = tid >> 3;                                          // 0..63
  const int scol = (((tid & 7) ^ ((tid >> 3) & 7)) << 4);             // cb ^ (row&7)<<4
  const char* Ag = (const char*)A;
  const char* Bg = (const char*)Bt;
  uint32_t offA[4], offB[4];
#pragma unroll
  for (int r = 0; r < 4; ++r) {
    offA[r] = (uint32_t)(m0 + srow + r * 64) * (K_DIM * 2) + scol;
    offB[r] = (uint32_t)(n0 + srow + r * 64) * (K_DIM * 2) + scol;
  }
  uint32_t ktA = 0, ktB = 0;   // byte offset along K of next tile to stage (BK*2 = 128)

  f32x4 acc[8][4];
#pragma unroll
  for (int m = 0; m < 8; ++m)
#pragma unroll
    for (int n = 0; n < 4; ++n) {
      f32x4 z = {0.f, 0.f, 0.f, 0.f};
      acc[m][n] = z;
    }

  // ---- prologue: stage T0 (A+B -> buf0), T1.B -> buf1; drain T0, keep T1.B in flight
  SA(0, 0); SA(0, 1); SA(0, 2); SA(0, 3);
  SB(0, 0); SB(0, 1); SB(0, 2); SB(0, 3);
  ktB = 128;
  SB(1, 0); SB(1, 1); SB(1, 2); SB(1, 3);
  ktA = 128; ktB = 256;
  VMCNT(4);
  BARRIER;

  bf16x8 a_r[4][2], b0[2][2], b1[2][2];

  for (int t = 0; t < NT; ++t) {
    const int cb = t & 1;
    const char* curA = ldsb + cb * 65536;
    const char* curB = curA + 32768;

    // first half-tile: A[mh0] x B[nh0..1]; stage T(t+1).A -> buf[cb^1]
    READ_A(0);
    READ_B(0, b0);
    if (t < NT - 1) { SA(cb ^ 1, 0); SA(cb ^ 1, 1); }
    MFMA_PH(0, 0, b0);

    READ_B(1, b1);
    if (t < NT - 1) { SA(cb ^ 1, 2); SA(cb ^ 1, 3); ktA += 128; }
    MFMA_PH(0, 1, b1);

    BARRIER;  // all waves consumed B[t] (b0,b1 in regs) -> B-region may be overwritten

    // second half-tile: A[mh1] x B[nh0..1]; stage T(t+2).B -> buf[cb] B-region
    READ_A(1);
    if (t < NT - 2) { SB(cb, 0); SB(cb, 1); }
    MFMA_PH(1, 0, b0);

    if (t < NT - 2) {
      SB(cb, 2); SB(cb, 3); ktB += 128;
      VMCNT(4);   // oldest [T+1.B, T+1.A] land; newest 4 (T+2.B) stay in flight
    } else {
      VMCNT(0);
    }
    MFMA_PH(1, 1, b1);

    BARRIER;  // tile end: A[t] consumed; T(t+1) fully in LDS
  }

  // ---- epilogue: C/D map col=lane&15, row=(lane>>4)*4+j ; fuse *scale + bias
  const float scale = scale_p[0];
#pragma unroll
  for (int n = 0; n < 4; ++n) {
    const int col = n0 + wc * 64 + n * 16 + l15;
    const float bv = bias[col];
#pragma unroll
    for (int m = 0; m < 8; ++m) {
      const int r0 = m0 + wr * 128 + m * 16 + lhi * 4;
      float* op = out + (size_t)r0 * N_DIM + col;
#pragma unroll
      for (int j = 0; j < 4; ++j) op[(size_t)j * N_DIM] = acc[m][n][j] * scale + bv;
    }
  }
}

extern "C" void kernel_launch(void* const* d_in, const int* in_sizes, int n_in,
                              void* d_out, int out_size, void* d_ws, size_t ws_size,
                              hipStream_t stream) {
  (void)in_sizes; (void)n_in; (void)out_size; (void)ws_size;
  const float* x    = (const float*)d_in[0];   // [4][2048][2048] f32
  const float* w    = (const float*)d_in[1];   // [2048][2048] f32
  const float* bias = (const float*)d_in[2];   // [2048] f32
  float* out = (float*)d_out;                  // [4][2048][2048] f32

  float* partials = (float*)d_ws;                              // 1024 f32
  float* scale_slot = partials + 1024;                         // 1 f32
  unsigned short* wt = (unsigned short*)((char*)d_ws + 8192);  // 8 MB bf16 W_t
  unsigned short* xb = (unsigned short*)((char*)d_ws + 8192 + (size_t)N_DIM * K_DIM * 2);  // 32 MB

  cvt_x_absum<<<17408, 256, 0, stream>>>(x, xb, w, partials);
  quant_w<<<4096, 256, 0, stream>>>(w, partials, wt, scale_slot);
  gemm_bt<<<256, 512, 0, stream>>>(xb, wt, bias, scale_slot, out);
}